// Round 18
// baseline (126.618 us; speedup 1.0000x reference)
//
#include <hip/hip_runtime.h>
#include <stdint.h>

typedef __attribute__((ext_vector_type(8))) short short8;
typedef __attribute__((ext_vector_type(4))) float f32x4;
typedef __attribute__((ext_vector_type(16))) float f32x16;

#define MFMA16(a, b, c) __builtin_amdgcn_mfma_f32_16x16x32_bf16((a), (b), (c), 0, 0, 0)
#define MFMA32(a, b, c) __builtin_amdgcn_mfma_f32_32x32x16_bf16((a), (b), (c), 0, 0, 0)

__device__ inline unsigned short f2bf(float x) {
  unsigned u = __float_as_uint(x);
  u = (u + 0x7FFFu + ((u >> 16) & 1u)) >> 16;
  return (unsigned short)u;
}

// async global->LDS, 16B per lane. LDS dest is wave-uniform base + lane*16.
__device__ inline void gload16(const unsigned short* g, unsigned short* l) {
  __builtin_amdgcn_global_load_lds(
      (const __attribute__((address_space(1))) unsigned int*)g,
      (__attribute__((address_space(3))) unsigned int*)l, 16, 0, 0);
}

__device__ inline short8 lds8(const unsigned short* base, int byteoff) {
  return *reinterpret_cast<const short8*>(reinterpret_cast<const char*>(base) + byteoff);
}

// pack two f32 -> one dword of 2 bf16 (RNE)
__device__ inline unsigned cvtpk(float lo, float hi) {
  unsigned r;
  asm("v_cvt_pk_bf16_f32 %0, %1, %2" : "=v"(r) : "v"(lo), "v"(hi));
  return r;
}
// swap vdst.hi32lanes <-> vsrc.lo32lanes
__device__ inline void plswap(unsigned& a, unsigned& b) {
  asm volatile("v_permlane32_swap_b32 %0, %1" : "+v"(a), "+v"(b));
}
__device__ inline float swapadd(float v) {
  float a = v, b;
  asm volatile("v_mov_b32 %1, %0\n\tv_permlane32_swap_b32 %0, %1" : "+v"(a), "=&v"(b));
  return a + b;
}

__device__ inline short8 mk8(unsigned a, unsigned b, unsigned c, unsigned d) {
  union { unsigned u[4]; short8 v; } x;
  x.u[0] = a; x.u[1] = b; x.u[2] = c; x.u[3] = d;
  return x.v;
}

// byte offset into a [rows][64] bf16 linear LDS tile, XOR-swizzled (GEMM tiles).
__device__ inline int swz(int row, int chunk) {
  return row * 128 + (((chunk) ^ (row & 7)) << 4);
}

// exp2 of 16 scores -> row-sum partial (in-lane tree) + two bf16 A-frags
__device__ inline void exppack(const f32x16& sv, float& lsum, short8& paLo, short8& paHi) {
  float p[16];
#pragma unroll
  for (int i = 0; i < 16; ++i) p[i] = __builtin_amdgcn_exp2f(sv[i]);
  float q8[8];
#pragma unroll
  for (int i = 0; i < 8; ++i) q8[i] = p[2 * i] + p[2 * i + 1];
#pragma unroll
  for (int s2 = 4; s2 > 0; s2 >>= 1)
#pragma unroll
    for (int i = 0; i < s2; ++i) q8[i] += q8[i + s2];
  lsum += q8[0];
  unsigned w0 = cvtpk(p[0], p[1]), w1 = cvtpk(p[2], p[3]);
  unsigned w2 = cvtpk(p[4], p[5]), w3 = cvtpk(p[6], p[7]);
  plswap(w0, w2); plswap(w1, w3);
  unsigned w4 = cvtpk(p[8], p[9]), w5 = cvtpk(p[10], p[11]);
  unsigned w6 = cvtpk(p[12], p[13]), w7 = cvtpk(p[14], p[15]);
  plswap(w4, w6); plswap(w5, w7);
  paLo = mk8(w0, w1, w2, w3);
  paHi = mk8(w4, w5, w6, w7);
}

// ---------------- fp32 -> bf16 conversion, 4 arrays in one launch ----------------
__global__ __launch_bounds__(256) void cvt_bf16x(const float* __restrict__ a0,
                                                 const float* __restrict__ a1,
                                                 const float* __restrict__ a2,
                                                 const float* __restrict__ a3,
                                                 unsigned short* __restrict__ d, int per) {
  int y = blockIdx.y;
  const float* s = (y == 0) ? a0 : (y == 1) ? a1 : (y == 2) ? a2 : a3;
  int i = (blockIdx.x * 256 + threadIdx.x) * 8;
  if (i >= per) return;
  float4 v0 = *reinterpret_cast<const float4*>(s + i);
  float4 v1 = *reinterpret_cast<const float4*>(s + i + 4);
  short8 o;
  o[0] = (short)f2bf(v0.x); o[1] = (short)f2bf(v0.y);
  o[2] = (short)f2bf(v0.z); o[3] = (short)f2bf(v0.w);
  o[4] = (short)f2bf(v1.x); o[5] = (short)f2bf(v1.y);
  o[6] = (short)f2bf(v1.z); o[7] = (short)f2bf(v1.w);
  *reinterpret_cast<short8*>(d + (size_t)y * per + i) = o;
}

// ---------------- GEMM: C = A @ W^T + bias, 2-phase pipelined, BN=64 (R14) --------
template <int MODE>
__global__ __launch_bounds__(256) void gemm_bt(
    const unsigned short* __restrict__ Abase, const unsigned short* __restrict__ Wbase,
    const float* __restrict__ bias0, const float* __restrict__ bias1,
    const float* __restrict__ bias2, unsigned short* __restrict__ ObaseBf,
    float* __restrict__ ObaseF, int M, int N, int K) {
  constexpr int CHUNK = (MODE == 0) ? 192 : 64;  // nwg/8 for XCD swizzle

  const int orig = blockIdx.x;
  const int wg = (orig & 7) * CHUNK + (orig >> 3);
  int z, bx, by;
  if (MODE == 0) {
    z = wg >> 9;
    int r = wg & 511;
    by = r & 15;   // by-fastest: 16 W-panels cycle within the XCD chunk
    bx = r >> 4;
  } else {
    z = 0; by = wg & 15; bx = wg >> 4;
  }

  const unsigned short* A = Abase + (size_t)z * M * K;
  const unsigned short* W = Wbase + (size_t)z * N * K;
  const float* bias = (z == 0) ? bias0 : (z == 1 ? bias1 : bias2);

  __shared__ unsigned short As[2 * 128 * 64];  // 32 KB
  __shared__ unsigned short Bs[2 * 64 * 64];   // 16 KB

  const int t = threadIdx.x;
  const int lane = t & 63, w = t >> 6;
  const int wm = w >> 1, wn = w & 1;
  const int m0 = bx * 128, n0 = by * 64;
  const int lrow = lane & 15, lg = lane >> 4;

  f32x4 acc[4][2] = {};

  int arow[4], acol[4], brow[2], bcol[2];
#pragma unroll
  for (int p = 0; p < 4; ++p) {
    int c = (p * 4 + w) * 64 + lane;
    arow[p] = c >> 3; acol[p] = ((c & 7) ^ (arow[p] & 7)) * 8;
  }
#pragma unroll
  for (int p = 0; p < 2; ++p) {
    int c = (p * 4 + w) * 64 + lane;
    brow[p] = c >> 3; bcol[p] = ((c & 7) ^ (brow[p] & 7)) * 8;
  }

#define STAGE_G(kt, buf)                                                              \
  {                                                                                   \
    _Pragma("unroll") for (int p = 0; p < 4; ++p)                                     \
        gload16(&A[(size_t)(m0 + arow[p]) * K + (kt) + acol[p]],                      \
                &As[(buf)*8192 + ((p * 4 + w) * 64) * 8]);                            \
    _Pragma("unroll") for (int p = 0; p < 2; ++p)                                     \
        gload16(&W[(size_t)(n0 + brow[p]) * K + (kt) + bcol[p]],                      \
                &Bs[(buf)*4096 + ((p * 4 + w) * 64) * 8]);                            \
  }

#define COMPUTE(buf)                                                                  \
  {                                                                                   \
    _Pragma("unroll") for (int kc = 0; kc < 2; ++kc) {                                \
      short8 af[4], bfr[2];                                                           \
      _Pragma("unroll") for (int i = 0; i < 4; ++i)                                   \
          af[i] = lds8(As, (buf)*16384 + swz(wm * 64 + i * 16 + lrow, kc * 4 + lg));  \
      _Pragma("unroll") for (int i = 0; i < 2; ++i)                                   \
          bfr[i] = lds8(Bs, (buf)*8192 + swz(wn * 32 + i * 16 + lrow, kc * 4 + lg));  \
      _Pragma("unroll") for (int mi = 0; mi < 4; ++mi)                                \
          _Pragma("unroll") for (int ni = 0; ni < 2; ++ni)                            \
              acc[mi][ni] = MFMA16(af[mi], bfr[ni], acc[mi][ni]);                     \
    }                                                                                 \
  }

  STAGE_G(0, 0);
  asm volatile("s_waitcnt vmcnt(0)" ::: "memory");
  __builtin_amdgcn_s_barrier();
  __builtin_amdgcn_sched_barrier(0);

  int cur = 0;
  for (int kt = 0; kt < K - 64; kt += 64) {
    STAGE_G(kt + 64, cur ^ 1);
    COMPUTE(cur);
    asm volatile("s_waitcnt vmcnt(0)" ::: "memory");
    __builtin_amdgcn_s_barrier();
    __builtin_amdgcn_sched_barrier(0);
    cur ^= 1;
  }
  COMPUTE(cur);  // peeled last step
#undef STAGE_G
#undef COMPUTE

  const int r0 = lg * 4;
  if (MODE == 0) {
    const float scale = (z == 0) ? 0.18033688011112042f : 1.0f;  // fold log2(e)/8 into Q
    if (z < 2) {
      unsigned short* O = ObaseBf + (size_t)z * (size_t)M * N;
#pragma unroll
      for (int mi = 0; mi < 4; ++mi)
#pragma unroll
        for (int ni = 0; ni < 2; ++ni) {
          int e = n0 + wn * 32 + ni * 16 + lrow;
          float be = bias[e];
          int h = e >> 6, d = e & 63;
#pragma unroll
          for (int r = 0; r < 4; ++r) {
            int m = m0 + wm * 64 + mi * 16 + r0 + r;
            int s = m >> 1, bb = m & 1;
            O[(((size_t)(bb * 16 + h) * 2048 + s) << 6) + d] = f2bf((acc[mi][ni][r] + be) * scale);
          }
        }
    } else {
      // V^T: LDS-staged coalesced writes (avoid 4KB-stride 2B scatter).
      __builtin_amdgcn_s_barrier();  // all waves done reading As (peeled COMPUTE)
      unsigned short* T = As;        // reuse: need 128*72 = 9216 ushorts (<16384)
      const int h = n0 >> 6;
#pragma unroll
      for (int mi = 0; mi < 4; ++mi)
#pragma unroll
        for (int ni = 0; ni < 2; ++ni) {
          int d = wn * 32 + ni * 16 + lrow;
          float be = bias[n0 + d];
#pragma unroll
          for (int r = 0; r < 4; ++r) {
            int mrel = wm * 64 + mi * 16 + r0 + r;   // 0..127
            int sl = mrel >> 1, bb = mrel & 1;
            T[(bb * 64 + d) * 72 + sl] = f2bf(acc[mi][ni][r] + be);
          }
        }
      __builtin_amdgcn_s_barrier();
      unsigned short* O = ObaseBf + (size_t)2 * (size_t)M * N;  // Vt[bh][d][s]
#pragma unroll
      for (int pass = 0; pass < 4; ++pass) {
        int rr = pass * 32 + (t >> 3);     // 0..127 = bb*64 + d
        int sl8 = (t & 7) * 8;
        short8 vv = *reinterpret_cast<const short8*>(&T[rr * 72 + sl8]);
        int bb = rr >> 6, d = rr & 63;
        *reinterpret_cast<short8*>(
            &O[(((size_t)(bb * 16 + h) * 64 + d) << 11) + (m0 >> 1) + sl8]) = vv;
      }
    }
  } else {
    float* O = ObaseF;
#pragma unroll
    for (int mi = 0; mi < 4; ++mi)
#pragma unroll
      for (int ni = 0; ni < 2; ++ni) {
        int e = n0 + wn * 32 + ni * 16 + lrow;
        float be = bias[e];
#pragma unroll
        for (int r = 0; r < 4; ++r) {
          int m = m0 + wm * 64 + mi * 16 + r0 + r;
          O[(size_t)m * N + e] = acc[mi][ni][r] + be;
        }
      }
  }
}

// ---------------- Flash attention, KBLK=128, strip-pipelined, V single-buffered ---
// Q (pre-scaled by log2(e)/8), K: [32][2048][64] bf16. Vt: [32][64][2048] bf16.
// ctx out: [S][B][1024] bf16. Grid 512, XCD-swizzled (4 bh/XCD). Block = 4 waves x
// 32 q-rows. 16 tiles of 128 keys. K ring-2 (32 KB) + V single buffer (16 KB) =
// 48 KB -> 3 blocks/CU. Per phase: stage V(t) early + K(t+1); QK01+exp0 cover V's
// latency; vmcnt(4) before PV (K's loads stay in flight); one barrier per phase.
__global__ __launch_bounds__(256, 3) void attn(const unsigned short* __restrict__ Q,
                                               const unsigned short* __restrict__ K,
                                               const unsigned short* __restrict__ Vt,
                                               unsigned short* __restrict__ ctx) {
  __shared__ unsigned short Ks[2 * 8192];  // ring-2: [buf][128 key][64 dk]
  __shared__ unsigned short Vs[8192];      // single: [64 d][128 key]

  // XCD swizzle: nwg=512, chunk=64 -> XCD x owns bh range [x*4, x*4+4)
  const int orig = blockIdx.x;
  const int wg = ((orig & 7) << 6) + (orig >> 3);
  const int bh = wg >> 4;
  const int qb = wg & 15;

  const int t = threadIdx.x, lane = t & 63, wv = t >> 6;
  const int q0 = qb * 128 + wv * 32;
  const int q = lane & 31, hi = lane >> 5;
  const int fq = (q ^ (q >> 3)) & 7;

  const unsigned short* Qb = Q + ((size_t)bh * 2048 + q0) * 64;
  const unsigned short* Kb = K + (size_t)bh * 2048 * 64;
  const unsigned short* Vb = Vt + (size_t)bh * 64 * 2048;

  short8 qf[4];
#pragma unroll
  for (int m = 0; m < 4; ++m)
    qf[m] = *reinterpret_cast<const short8*>(&Qb[q * 64 + m * 16 + hi * 8]);

  // K read offsets: strip st (32 keys), k-chunk m. row = st*32+q, g = fq^((st&1)*4).
  int koff[4][4];
#pragma unroll
  for (int st = 0; st < 4; ++st) {
    int f = fq ^ ((st & 1) * 4);
#pragma unroll
    for (int m = 0; m < 4; ++m)
      koff[st][m] = (st * 32 + q) * 128 + (((m * 2 + hi) ^ f) << 4);
  }
  // V read offsets: row = dh*32+q (256B rows), cir = st*4+kc*2+hi in [0,16),
  // swizzled on low-3 bits with g = fq^(dh*4).
  int voff[2][4][2];
#pragma unroll
  for (int dh = 0; dh < 2; ++dh) {
    int g = fq ^ (dh * 4);
#pragma unroll
    for (int st = 0; st < 4; ++st)
#pragma unroll
      for (int kc = 0; kc < 2; ++kc) {
        int cir = st * 4 + kc * 2 + hi;
        int scir = (cir & 8) | ((cir & 7) ^ g);
        voff[dh][st][kc] = (dh * 32 + q) * 256 + (scir << 4);
      }
  }

  // staging sources (pre-inverse-swizzled with the same g involutions)
  const unsigned short* ksp[4];
  const unsigned short* vpp[4];
#pragma unroll
  for (int p = 0; p < 4; ++p) {
    int c = (p * 4 + wv) * 64 + lane;          // 0..1023
    int kr = c >> 3, kcc = c & 7;              // K: 128 rows x 8 chunks
    int gk = (kr ^ (kr >> 3)) & 7;
    ksp[p] = Kb + (size_t)kr * 64 + (kcc ^ gk) * 8;
    int vr = c >> 4, cir = c & 15;             // V: 64 rows x 16 chunks
    int gv = (vr ^ (vr >> 3)) & 7;
    int scir = (cir & 8) | ((cir & 7) ^ gv);
    vpp[p] = Vb + (size_t)vr * 2048 + scir * 8;
  }

#define STAGE_K(buf)                                                         \
  {                                                                          \
    _Pragma("unroll") for (int p = 0; p < 4; ++p) {                          \
      gload16(ksp[p], &Ks[(buf)*8192 + ((p * 4 + wv) * 64) * 8]);            \
      ksp[p] += 8192;                                                        \
    }                                                                        \
  }
#define STAGE_V()                                                            \
  {                                                                          \
    _Pragma("unroll") for (int p = 0; p < 4; ++p) {                          \
      gload16(vpp[p], &Vs[((p * 4 + wv) * 64) * 8]);                         \
      vpp[p] += 128;                                                         \
    }                                                                        \
  }

#define QK(st, sv)                                                           \
  {                                                                          \
    _Pragma("unroll") for (int m = 0; m < 4; ++m)                            \
        sv = MFMA32(lds8(Ks, cb + koff[st][m]), qf[m], sv);                  \
  }

#define PV(st, pl, ph)                                                       \
  {                                                                          \
    oa0 = MFMA32(pl, lds8(Vs, voff[0][st][0]), oa0);                         \
    oa1 = MFMA32(pl, lds8(Vs, voff[1][st][0]), oa1);                         \
    oa0 = MFMA32(ph, lds8(Vs, voff[0][st][1]), oa0);                         \
    oa1 = MFMA32(ph, lds8(Vs, voff[1][st][1]), oa1);                         \
  }

  f32x16 oa0 = {}, oa1 = {};
  float lsum = 0.f;

  // prologue: stage K(0), drain, rendezvous
  STAGE_K(0);
  asm volatile("s_waitcnt vmcnt(0)" ::: "memory");
  __builtin_amdgcn_s_barrier();
  __builtin_amdgcn_sched_barrier(0);

  for (int tile = 0; tile < 15; ++tile) {
    const int cb = (tile & 1) * 16384;  // K buffer byte offset
    STAGE_V();                          // V(t): consumed mid-phase (vmcnt(4))
    STAGE_K((tile & 1) ^ 1);            // K(t+1): consumed next phase

    __builtin_amdgcn_s_setprio(1);
    f32x16 s0 = {}, s1 = {}, s2 = {}, s3 = {};
    short8 pl, ph;
    QK(0, s0);
    QK(1, s1);
    exppack(s0, lsum, pl, ph);
    // V(t)'s 4 loads retired; K(t+1)'s 4 remain in flight across the phase
    asm volatile("s_waitcnt vmcnt(4)" ::: "memory");
    __builtin_amdgcn_sched_barrier(0);
    PV(0, pl, ph);
    QK(2, s2);
    exppack(s1, lsum, pl, ph);
    PV(1, pl, ph);
    QK(3, s3);
    exppack(s2, lsum, pl, ph);
    PV(2, pl, ph);
    exppack(s3, lsum, pl, ph);
    PV(3, pl, ph);
    __builtin_amdgcn_s_setprio(0);

    // K(t+1) landed (issued a full phase ago); all waves done with K(t)/V(t)
    asm volatile("s_waitcnt vmcnt(0)" ::: "memory");
    __builtin_amdgcn_sched_barrier(0);
    __builtin_amdgcn_s_barrier();
    __builtin_amdgcn_sched_barrier(0);
  }
  {  // tail tile 15: K resident (slot 1), stage V only, drain V before PV
    const int cb = 16384;
    STAGE_V();
    __builtin_amdgcn_s_setprio(1);
    f32x16 s0 = {}, s1 = {}, s2 = {}, s3 = {};
    short8 pl, ph;
    QK(0, s0);
    QK(1, s1);
    exppack(s0, lsum, pl, ph);
    asm volatile("s_waitcnt vmcnt(0)" ::: "memory");
    __builtin_amdgcn_sched_barrier(0);
    PV(0, pl, ph);
    QK(2, s2);
    exppack(s1, lsum, pl, ph);
    PV(1, pl, ph);
    QK(3, s3);
    exppack(s2, lsum, pl, ph);
    PV(2, pl, ph);
    exppack(s3, lsum, pl, ph);
    PV(3, pl, ph);
    __builtin_amdgcn_s_setprio(0);
  }
#undef STAGE_K
#undef STAGE_V
#undef QK
#undef PV

  // epilogue: combine hi/lo key-half sums, normalize, store
  lsum = swapadd(lsum);
  float linv = 1.0f / lsum;
  const int b = bh >> 4, h = bh & 15;
#pragma unroll
  for (int r = 0; r < 16; ++r) {
    int qr = (r & 3) + 8 * (r >> 2) + 4 * hi;
    float li = __shfl(linv, qr);
    size_t base = ((size_t)(q0 + qr) * 2 + b) * 1024 + h * 64 + q;
    ctx[base] = f2bf(oa0[r] * li);
    ctx[base + 32] = f2bf(oa1[r] * li);
  }
}

// ---------------- host ----------------
extern "C" void kernel_launch(void* const* d_in, const int* in_sizes, int n_in, void* d_out,
                              int out_size, void* d_ws, size_t ws_size, hipStream_t stream) {
  const float* q  = (const float*)d_in[0];
  const float* k  = (const float*)d_in[1];
  const float* v  = (const float*)d_in[2];
  const float* Wq = (const float*)d_in[3];
  const float* bq = (const float*)d_in[4];
  const float* Wk = (const float*)d_in[5];
  const float* bk = (const float*)d_in[6];
  const float* Wv = (const float*)d_in[7];
  const float* bv = (const float*)d_in[8];
  const float* Wo = (const float*)d_in[9];
  const float* bo = (const float*)d_in[10];

  const size_t SZ_IN = 4194304;  // 4096*1024
  const size_t SZ_W  = 1048576;  // 1024*1024
  unsigned short* ws  = (unsigned short*)d_ws;
  unsigned short* xb  = ws;                 // q,k,v bf16       (3*SZ_IN)
  unsigned short* Wb  = xb + 3 * SZ_IN;     // Wq,Wk,Wv,Wo bf16 (4*SZ_W)
  unsigned short* QKV = Wb + 4 * SZ_W;      // Q,K (by-head), Vt (transposed)
  unsigned short* ctx = QKV + 3 * SZ_IN;    // context          (SZ_IN)

  cvt_bf16x<<<dim3(SZ_IN / 2048, 3), 256, 0, stream>>>(q, k, v, v, xb, (int)SZ_IN);
  cvt_bf16x<<<dim3(SZ_W / 2048, 4), 256, 0, stream>>>(Wq, Wk, Wv, Wo, Wb, (int)SZ_W);

  gemm_bt<0><<<1536, 256, 0, stream>>>(xb, Wb, bq, bk, bv, QKV, nullptr, 4096, 1024, 1024);
  attn<<<512, 256, 0, stream>>>(QKV, QKV + SZ_IN, QKV + 2 * SZ_IN, ctx);
  gemm_bt<1><<<512, 256, 0, stream>>>(ctx, Wb + 3 * SZ_W, bo, bo, bo, nullptr,
                                      (float*)d_out, 4096, 1024, 1024);
}

// Round 19
// 114.635 us; speedup vs baseline: 1.1045x; 1.1045x over previous
//
#include <hip/hip_runtime.h>
#include <stdint.h>

typedef __attribute__((ext_vector_type(8))) short short8;
typedef __attribute__((ext_vector_type(4))) float f32x4;
typedef __attribute__((ext_vector_type(16))) float f32x16;

#define MFMA16(a, b, c) __builtin_amdgcn_mfma_f32_16x16x32_bf16((a), (b), (c), 0, 0, 0)
#define MFMA32(a, b, c) __builtin_amdgcn_mfma_f32_32x32x16_bf16((a), (b), (c), 0, 0, 0)

__device__ inline unsigned short f2bf(float x) {
  unsigned u = __float_as_uint(x);
  u = (u + 0x7FFFu + ((u >> 16) & 1u)) >> 16;
  return (unsigned short)u;
}

// async global->LDS, 16B per lane. LDS dest is wave-uniform base + lane*16.
__device__ inline void gload16(const unsigned short* g, unsigned short* l) {
  __builtin_amdgcn_global_load_lds(
      (const __attribute__((address_space(1))) unsigned int*)g,
      (__attribute__((address_space(3))) unsigned int*)l, 16, 0, 0);
}

__device__ inline short8 lds8(const unsigned short* base, int byteoff) {
  return *reinterpret_cast<const short8*>(reinterpret_cast<const char*>(base) + byteoff);
}

// pack two f32 -> one dword of 2 bf16 (RNE)
__device__ inline unsigned cvtpk(float lo, float hi) {
  unsigned r;
  asm("v_cvt_pk_bf16_f32 %0, %1, %2" : "=v"(r) : "v"(lo), "v"(hi));
  return r;
}
// swap vdst.hi32lanes <-> vsrc.lo32lanes
__device__ inline void plswap(unsigned& a, unsigned& b) {
  asm volatile("v_permlane32_swap_b32 %0, %1" : "+v"(a), "+v"(b));
}
__device__ inline float swapadd(float v) {
  float a = v, b;
  asm volatile("v_mov_b32 %1, %0\n\tv_permlane32_swap_b32 %0, %1" : "+v"(a), "=&v"(b));
  return a + b;
}

__device__ inline short8 mk8(unsigned a, unsigned b, unsigned c, unsigned d) {
  union { unsigned u[4]; short8 v; } x;
  x.u[0] = a; x.u[1] = b; x.u[2] = c; x.u[3] = d;
  return x.v;
}

// byte offset into a [rows][64] bf16 linear LDS tile, XOR-swizzled (GEMM tiles).
__device__ inline int swz(int row, int chunk) {
  return row * 128 + (((chunk) ^ (row & 7)) << 4);
}

// exp2 of 16 scores -> row-sum partial (in-lane tree) + two bf16 A-frags
__device__ inline void exppack(const f32x16& sv, float& lsum, short8& paLo, short8& paHi) {
  float p[16];
#pragma unroll
  for (int i = 0; i < 16; ++i) p[i] = __builtin_amdgcn_exp2f(sv[i]);
  float q8[8];
#pragma unroll
  for (int i = 0; i < 8; ++i) q8[i] = p[2 * i] + p[2 * i + 1];
#pragma unroll
  for (int s2 = 4; s2 > 0; s2 >>= 1)
#pragma unroll
    for (int i = 0; i < s2; ++i) q8[i] += q8[i + s2];
  lsum += q8[0];
  unsigned w0 = cvtpk(p[0], p[1]), w1 = cvtpk(p[2], p[3]);
  unsigned w2 = cvtpk(p[4], p[5]), w3 = cvtpk(p[6], p[7]);
  plswap(w0, w2); plswap(w1, w3);
  unsigned w4 = cvtpk(p[8], p[9]), w5 = cvtpk(p[10], p[11]);
  unsigned w6 = cvtpk(p[12], p[13]), w7 = cvtpk(p[14], p[15]);
  plswap(w4, w6); plswap(w5, w7);
  paLo = mk8(w0, w1, w2, w3);
  paHi = mk8(w4, w5, w6, w7);
}

// ---------------- fp32 -> bf16 conversion, ALL 7 arrays in one launch -------------
// y in [0,3): inputs q/k/v (4194304 elems each) -> xb + y*SZ_IN
// y in [3,7): weights Wq/Wk/Wv/Wo (1048576 each) -> Wb + (y-3)*SZ_W
__global__ __launch_bounds__(256) void cvt_all(
    const float* __restrict__ a0, const float* __restrict__ a1, const float* __restrict__ a2,
    const float* __restrict__ w0, const float* __restrict__ w1, const float* __restrict__ w2,
    const float* __restrict__ w3, unsigned short* __restrict__ xb,
    unsigned short* __restrict__ Wb) {
  const int y = blockIdx.y;
  const float* s;
  unsigned short* d;
  int per;
  if (y < 3) {
    s = (y == 0) ? a0 : (y == 1) ? a1 : a2;
    d = xb + (size_t)y * 4194304;
    per = 4194304;
  } else {
    int z = y - 3;
    s = (z == 0) ? w0 : (z == 1) ? w1 : (z == 2) ? w2 : w3;
    d = Wb + (size_t)z * 1048576;
    per = 1048576;
  }
  int i = (blockIdx.x * 256 + threadIdx.x) * 8;
  if (i >= per) return;
  float4 v0 = *reinterpret_cast<const float4*>(s + i);
  float4 v1 = *reinterpret_cast<const float4*>(s + i + 4);
  short8 o;
  o[0] = (short)f2bf(v0.x); o[1] = (short)f2bf(v0.y);
  o[2] = (short)f2bf(v0.z); o[3] = (short)f2bf(v0.w);
  o[4] = (short)f2bf(v1.x); o[5] = (short)f2bf(v1.y);
  o[6] = (short)f2bf(v1.z); o[7] = (short)f2bf(v1.w);
  *reinterpret_cast<short8*>(d + i) = o;
}

// ---------------- GEMM: C = A @ W^T + bias, 2-phase pipelined, BN=64 (R14) --------
template <int MODE>
__global__ __launch_bounds__(256) void gemm_bt(
    const unsigned short* __restrict__ Abase, const unsigned short* __restrict__ Wbase,
    const float* __restrict__ bias0, const float* __restrict__ bias1,
    const float* __restrict__ bias2, unsigned short* __restrict__ ObaseBf,
    float* __restrict__ ObaseF, int M, int N, int K) {
  constexpr int CHUNK = (MODE == 0) ? 192 : 64;  // nwg/8 for XCD swizzle

  const int orig = blockIdx.x;
  const int wg = (orig & 7) * CHUNK + (orig >> 3);
  int z, bx, by;
  if (MODE == 0) {
    z = wg >> 9;
    int r = wg & 511;
    by = r & 15;   // by-fastest: 16 W-panels cycle within the XCD chunk
    bx = r >> 4;
  } else {
    z = 0; by = wg & 15; bx = wg >> 4;
  }

  const unsigned short* A = Abase + (size_t)z * M * K;
  const unsigned short* W = Wbase + (size_t)z * N * K;
  const float* bias = (z == 0) ? bias0 : (z == 1 ? bias1 : bias2);

  __shared__ unsigned short As[2 * 128 * 64];  // 32 KB
  __shared__ unsigned short Bs[2 * 64 * 64];   // 16 KB

  const int t = threadIdx.x;
  const int lane = t & 63, w = t >> 6;
  const int wm = w >> 1, wn = w & 1;
  const int m0 = bx * 128, n0 = by * 64;
  const int lrow = lane & 15, lg = lane >> 4;

  f32x4 acc[4][2] = {};

  int arow[4], acol[4], brow[2], bcol[2];
#pragma unroll
  for (int p = 0; p < 4; ++p) {
    int c = (p * 4 + w) * 64 + lane;
    arow[p] = c >> 3; acol[p] = ((c & 7) ^ (arow[p] & 7)) * 8;
  }
#pragma unroll
  for (int p = 0; p < 2; ++p) {
    int c = (p * 4 + w) * 64 + lane;
    brow[p] = c >> 3; bcol[p] = ((c & 7) ^ (brow[p] & 7)) * 8;
  }

#define STAGE_G(kt, buf)                                                              \
  {                                                                                   \
    _Pragma("unroll") for (int p = 0; p < 4; ++p)                                     \
        gload16(&A[(size_t)(m0 + arow[p]) * K + (kt) + acol[p]],                      \
                &As[(buf)*8192 + ((p * 4 + w) * 64) * 8]);                            \
    _Pragma("unroll") for (int p = 0; p < 2; ++p)                                     \
        gload16(&W[(size_t)(n0 + brow[p]) * K + (kt) + bcol[p]],                      \
                &Bs[(buf)*4096 + ((p * 4 + w) * 64) * 8]);                            \
  }

#define COMPUTE(buf)                                                                  \
  {                                                                                   \
    _Pragma("unroll") for (int kc = 0; kc < 2; ++kc) {                                \
      short8 af[4], bfr[2];                                                           \
      _Pragma("unroll") for (int i = 0; i < 4; ++i)                                   \
          af[i] = lds8(As, (buf)*16384 + swz(wm * 64 + i * 16 + lrow, kc * 4 + lg));  \
      _Pragma("unroll") for (int i = 0; i < 2; ++i)                                   \
          bfr[i] = lds8(Bs, (buf)*8192 + swz(wn * 32 + i * 16 + lrow, kc * 4 + lg));  \
      _Pragma("unroll") for (int mi = 0; mi < 4; ++mi)                                \
          _Pragma("unroll") for (int ni = 0; ni < 2; ++ni)                            \
              acc[mi][ni] = MFMA16(af[mi], bfr[ni], acc[mi][ni]);                     \
    }                                                                                 \
  }

  STAGE_G(0, 0);
  asm volatile("s_waitcnt vmcnt(0)" ::: "memory");
  __builtin_amdgcn_s_barrier();
  __builtin_amdgcn_sched_barrier(0);

  int cur = 0;
  for (int kt = 0; kt < K - 64; kt += 64) {
    STAGE_G(kt + 64, cur ^ 1);
    COMPUTE(cur);
    asm volatile("s_waitcnt vmcnt(0)" ::: "memory");
    __builtin_amdgcn_s_barrier();
    __builtin_amdgcn_sched_barrier(0);
    cur ^= 1;
  }
  COMPUTE(cur);  // peeled last step
#undef STAGE_G
#undef COMPUTE

  const int r0 = lg * 4;
  if (MODE == 0) {
    const float scale = (z == 0) ? 0.18033688011112042f : 1.0f;  // fold log2(e)/8 into Q
    if (z < 2) {
      unsigned short* O = ObaseBf + (size_t)z * (size_t)M * N;
#pragma unroll
      for (int mi = 0; mi < 4; ++mi)
#pragma unroll
        for (int ni = 0; ni < 2; ++ni) {
          int e = n0 + wn * 32 + ni * 16 + lrow;
          float be = bias[e];
          int h = e >> 6, d = e & 63;
#pragma unroll
          for (int r = 0; r < 4; ++r) {
            int m = m0 + wm * 64 + mi * 16 + r0 + r;
            int s = m >> 1, bb = m & 1;
            O[(((size_t)(bb * 16 + h) * 2048 + s) << 6) + d] = f2bf((acc[mi][ni][r] + be) * scale);
          }
        }
    } else {
      // V^T: LDS-staged coalesced writes (avoid 4KB-stride 2B scatter).
      __builtin_amdgcn_s_barrier();  // all waves done reading As (peeled COMPUTE)
      unsigned short* T = As;        // reuse: need 128*72 = 9216 ushorts (<16384)
      const int h = n0 >> 6;
#pragma unroll
      for (int mi = 0; mi < 4; ++mi)
#pragma unroll
        for (int ni = 0; ni < 2; ++ni) {
          int d = wn * 32 + ni * 16 + lrow;
          float be = bias[n0 + d];
#pragma unroll
          for (int r = 0; r < 4; ++r) {
            int mrel = wm * 64 + mi * 16 + r0 + r;   // 0..127
            int sl = mrel >> 1, bb = mrel & 1;
            T[(bb * 64 + d) * 72 + sl] = f2bf(acc[mi][ni][r] + be);
          }
        }
      __builtin_amdgcn_s_barrier();
      unsigned short* O = ObaseBf + (size_t)2 * (size_t)M * N;  // Vt[bh][d][s]
#pragma unroll
      for (int pass = 0; pass < 4; ++pass) {
        int rr = pass * 32 + (t >> 3);     // 0..127 = bb*64 + d
        int sl8 = (t & 7) * 8;
        short8 vv = *reinterpret_cast<const short8*>(&T[rr * 72 + sl8]);
        int bb = rr >> 6, d = rr & 63;
        *reinterpret_cast<short8*>(
            &O[(((size_t)(bb * 16 + h) * 64 + d) << 11) + (m0 >> 1) + sl8]) = vv;
      }
    }
  } else {
    float* O = ObaseF;
#pragma unroll
    for (int mi = 0; mi < 4; ++mi)
#pragma unroll
      for (int ni = 0; ni < 2; ++ni) {
        int e = n0 + wn * 32 + ni * 16 + lrow;
        float be = bias[e];
#pragma unroll
        for (int r = 0; r < 4; ++r) {
          int m = m0 + wm * 64 + mi * 16 + r0 + r;
          O[(size_t)m * N + e] = acc[mi][ni][r] + be;
        }
      }
  }
}

// ---------------- Flash attention, KBLK=128, strip-pipelined (R16) ----------------
// Q (pre-scaled by log2(e)/8), K: [32][2048][64] bf16. Vt: [32][64][2048] bf16.
// ctx out: [S][B][1024] bf16. Grid 512, XCD-swizzled (4 bh/XCD).
// Block = 4 waves x 32 q-rows. 16 tiles of 128 keys; ring-2 LDS (64 KB total,
// 2 blocks/CU). Per phase: STAGE(t+1) -> 4-strip pipeline {QK(s+1) MFMA overlaps
// exp(s) VALU; PV(s)} -> one vmcnt(0)+barrier.
__global__ __launch_bounds__(256, 2) void attn(const unsigned short* __restrict__ Q,
                                               const unsigned short* __restrict__ K,
                                               const unsigned short* __restrict__ Vt,
                                               unsigned short* __restrict__ ctx) {
  __shared__ unsigned short Ks[2 * 8192];  // [buf][128 key][64 dk]
  __shared__ unsigned short Vs[2 * 8192];  // [buf][64 d][128 key]

  // XCD swizzle: nwg=512, chunk=64 -> XCD x owns bh range [x*4, x*4+4)
  const int orig = blockIdx.x;
  const int wg = ((orig & 7) << 6) + (orig >> 3);
  const int bh = wg >> 4;
  const int qb = wg & 15;

  const int t = threadIdx.x, lane = t & 63, wv = t >> 6;
  const int q0 = qb * 128 + wv * 32;
  const int q = lane & 31, hi = lane >> 5;
  const int fq = (q ^ (q >> 3)) & 7;

  const unsigned short* Qb = Q + ((size_t)bh * 2048 + q0) * 64;
  const unsigned short* Kb = K + (size_t)bh * 2048 * 64;
  const unsigned short* Vb = Vt + (size_t)bh * 64 * 2048;

  short8 qf[4];
#pragma unroll
  for (int m = 0; m < 4; ++m)
    qf[m] = *reinterpret_cast<const short8*>(&Qb[q * 64 + m * 16 + hi * 8]);

  // K read offsets: strip st (32 keys), k-chunk m. row = st*32+q, g = fq^((st&1)*4).
  int koff[4][4];
#pragma unroll
  for (int st = 0; st < 4; ++st) {
    int f = fq ^ ((st & 1) * 4);
#pragma unroll
    for (int m = 0; m < 4; ++m)
      koff[st][m] = (st * 32 + q) * 128 + (((m * 2 + hi) ^ f) << 4);
  }
  // V read offsets: row = dh*32+q (256B rows), cir = st*4+kc*2+hi in [0,16),
  // swizzled on low-3 bits with g = fq^(dh*4).
  int voff[2][4][2];
#pragma unroll
  for (int dh = 0; dh < 2; ++dh) {
    int g = fq ^ (dh * 4);
#pragma unroll
    for (int st = 0; st < 4; ++st)
#pragma unroll
      for (int kc = 0; kc < 2; ++kc) {
        int cir = st * 4 + kc * 2 + hi;
        int scir = (cir & 8) | ((cir & 7) ^ g);
        voff[dh][st][kc] = (dh * 32 + q) * 256 + (scir << 4);
      }
  }

  // staging sources (pre-inverse-swizzled with the same g involutions)
  const unsigned short* ksp[4];
  const unsigned short* vpp[4];
#pragma unroll
  for (int p = 0; p < 4; ++p) {
    int c = (p * 4 + wv) * 64 + lane;          // 0..1023
    int kr = c >> 3, kcc = c & 7;              // K: 128 rows x 8 chunks
    int gk = (kr ^ (kr >> 3)) & 7;
    ksp[p] = Kb + (size_t)kr * 64 + (kcc ^ gk) * 8;
    int vr = c >> 4, cir = c & 15;             // V: 64 rows x 16 chunks
    int gv = (vr ^ (vr >> 3)) & 7;
    int scir = (cir & 8) | ((cir & 7) ^ gv);
    vpp[p] = Vb + (size_t)vr * 2048 + scir * 8;
  }

#define STAGE(buf)                                                           \
  {                                                                          \
    _Pragma("unroll") for (int p = 0; p < 4; ++p)                            \
        gload16(ksp[p], &Ks[(buf)*8192 + ((p * 4 + wv) * 64) * 8]);          \
    _Pragma("unroll") for (int p = 0; p < 4; ++p)                            \
        gload16(vpp[p], &Vs[(buf)*8192 + ((p * 4 + wv) * 64) * 8]);          \
    _Pragma("unroll") for (int p = 0; p < 4; ++p) { ksp[p] += 8192; vpp[p] += 128; } \
  }

#define QK(st, sv)                                                           \
  {                                                                          \
    _Pragma("unroll") for (int m = 0; m < 4; ++m)                            \
        sv = MFMA32(lds8(Ks, cb + koff[st][m]), qf[m], sv);                  \
  }

#define PV(st, pl, ph)                                                       \
  {                                                                          \
    oa0 = MFMA32(pl, lds8(Vs, cb + voff[0][st][0]), oa0);                    \
    oa1 = MFMA32(pl, lds8(Vs, cb + voff[1][st][0]), oa1);                    \
    oa0 = MFMA32(ph, lds8(Vs, cb + voff[0][st][1]), oa0);                    \
    oa1 = MFMA32(ph, lds8(Vs, cb + voff[1][st][1]), oa1);                    \
  }

  f32x16 oa0 = {}, oa1 = {};
  float lsum = 0.f;

  // prologue: stage tile 0, drain, rendezvous
  STAGE(0);
  asm volatile("s_waitcnt vmcnt(0)" ::: "memory");
  __builtin_amdgcn_s_barrier();
  __builtin_amdgcn_sched_barrier(0);

  for (int tile = 0; tile < 16; ++tile) {
    const int cb = (tile & 1) * 16384;  // byte offset of current buffer
    if (tile < 15) STAGE((tile & 1) ^ 1);

    __builtin_amdgcn_s_setprio(1);
    f32x16 s0 = {}, s1 = {}, s2 = {}, s3 = {};
    short8 pl, ph;
    QK(0, s0);
    QK(1, s1);
    exppack(s0, lsum, pl, ph);
    PV(0, pl, ph);
    QK(2, s2);
    exppack(s1, lsum, pl, ph);
    PV(1, pl, ph);
    QK(3, s3);
    exppack(s2, lsum, pl, ph);
    PV(2, pl, ph);
    exppack(s3, lsum, pl, ph);
    PV(3, pl, ph);
    __builtin_amdgcn_s_setprio(0);

    if (tile < 15) {
      // next tile's loads landed (issued a full phase ago); all waves done
      // reading buf[cur] before it is overwritten next phase
      asm volatile("s_waitcnt vmcnt(0)" ::: "memory");
      __builtin_amdgcn_sched_barrier(0);
      __builtin_amdgcn_s_barrier();
      __builtin_amdgcn_sched_barrier(0);
    }
  }
#undef STAGE
#undef QK
#undef PV

  // epilogue: combine hi/lo key-half sums, normalize, store
  lsum = swapadd(lsum);
  float linv = 1.0f / lsum;
  const int b = bh >> 4, h = bh & 15;
#pragma unroll
  for (int r = 0; r < 16; ++r) {
    int qr = (r & 3) + 8 * (r >> 2) + 4 * hi;
    float li = __shfl(linv, qr);
    size_t base = ((size_t)(q0 + qr) * 2 + b) * 1024 + h * 64 + q;
    ctx[base] = f2bf(oa0[r] * li);
    ctx[base + 32] = f2bf(oa1[r] * li);
  }
}

// ---------------- host ----------------
extern "C" void kernel_launch(void* const* d_in, const int* in_sizes, int n_in, void* d_out,
                              int out_size, void* d_ws, size_t ws_size, hipStream_t stream) {
  const float* q  = (const float*)d_in[0];
  const float* k  = (const float*)d_in[1];
  const float* v  = (const float*)d_in[2];
  const float* Wq = (const float*)d_in[3];
  const float* bq = (const float*)d_in[4];
  const float* Wk = (const float*)d_in[5];
  const float* bk = (const float*)d_in[6];
  const float* Wv = (const float*)d_in[7];
  const float* bv = (const float*)d_in[8];
  const float* Wo = (const float*)d_in[9];
  const float* bo = (const float*)d_in[10];

  const size_t SZ_IN = 4194304;  // 4096*1024
  const size_t SZ_W  = 1048576;  // 1024*1024
  unsigned short* ws  = (unsigned short*)d_ws;
  unsigned short* xb  = ws;                 // q,k,v bf16       (3*SZ_IN)
  unsigned short* Wb  = xb + 3 * SZ_IN;     // Wq,Wk,Wv,Wo bf16 (4*SZ_W)
  unsigned short* QKV = Wb + 4 * SZ_W;      // Q,K (by-head), Vt (transposed)
  unsigned short* ctx = QKV + 3 * SZ_IN;    // context          (SZ_IN)

  cvt_all<<<dim3(SZ_IN / 2048, 7), 256, 0, stream>>>(q, k, v, Wq, Wk, Wv, Wo, xb, Wb);

  gemm_bt<0><<<1536, 256, 0, stream>>>(xb, Wb, bq, bk, bv, QKV, nullptr, 4096, 1024, 1024);
  attn<<<512, 256, 0, stream>>>(QKV, QKV + SZ_IN, QKV + 2 * SZ_IN, ctx);
  gemm_bt<1><<<512, 256, 0, stream>>>(ctx, Wb + 3 * SZ_W, bo, bo, bo, nullptr,
                                      (float*)d_out, 4096, 1024, 1024);
}